// Round 5
// baseline (328.079 us; speedup 1.0000x reference)
//
#include <hip/hip_runtime.h>

#define N1 8192
#define N2 8192
#define DIM 256
#define BM 256           // tile M = tile N = 256
#define KH 64            // halves per K-step (BK)
#define KSTEPS (DIM / KH)   // 4

typedef _Float16 half8 __attribute__((ext_vector_type(8)));
typedef _Float16 half4v __attribute__((ext_vector_type(4)));
typedef float f32x4 __attribute__((ext_vector_type(4)));

// Async global->LDS, 16B per lane. LDS dest is wave-uniform base + lane*16.
__device__ __forceinline__ void async_load16(const void* g, void* lds) {
    __builtin_amdgcn_global_load_lds(
        (__attribute__((address_space(1))) void*)g,
        (__attribute__((address_space(3))) void*)lds,
        16, 0, 0);
}

// --- Kernel 1: column mean of x1 (adj pre-zeroed). 512 blocks x 16 rows. ---
__global__ __launch_bounds__(256) void colmean_kernel(const float* __restrict__ x1,
                                                      float* __restrict__ adj) {
    int t = threadIdx.x;                  // dim index 0..255 (coalesced per row)
    size_t r0 = (size_t)blockIdx.x * 16;
    float s = 0.f;
    #pragma unroll
    for (int r = 0; r < 16; ++r) s += x1[(r0 + r) * DIM + t];
    atomicAdd(&adj[t], s * (1.0f / (float)N1));
}

// --- Kernel 2: center/scale/quantize to fp16 + row sq-norms. One wave per row. ---
__global__ __launch_bounds__(256) void quant_kernel(
    const float* __restrict__ x1, const float* __restrict__ x2,
    const float* __restrict__ adj, const float* __restrict__ ls,
    _Float16* __restrict__ y1, _Float16* __restrict__ y2,
    float* __restrict__ sq1, float* __restrict__ sq2) {
    int wave = threadIdx.x >> 6, lane = threadIdx.x & 63;
    int grow = blockIdx.x * 4 + wave;
    const float* x; _Float16* y; float* sq; int row;
    if (grow < N1) { x = x1; y = y1; sq = sq1; row = grow; }
    else           { x = x2; y = y2; sq = sq2; row = grow - N1; }
    int c = lane * 4;
    f32x4 xv = *(const f32x4*)&x[(size_t)row * DIM + c];
    f32x4 av = *(const f32x4*)&adj[c];
    f32x4 lv = *(const f32x4*)&ls[c];
    half4v h;
    float p = 0.f;
    #pragma unroll
    for (int u = 0; u < 4; ++u) {
        float v = (xv[u] - av[u]) / lv[u];
        _Float16 hh = (_Float16)v;
        h[u] = hh;
        float f = (float)hh;
        p += f * f;
    }
    *(half4v*)&y[(size_t)row * DIM + c] = h;
    #pragma unroll
    for (int off = 32; off > 0; off >>= 1) p += __shfl_down(p, off, 64);
    if (lane == 0) sq[row] = p;
}

// --- Kernel 3: 256x256-tile 8-wave MFMA GEMM (R4 schedule) + LDS-bounce
//     epilogue producing fully contiguous 1KB-per-instruction output stores. ---
// K-loop identical to R4 (best so far): BM=BN=256, BK=64, 8 waves (2Mx4N),
// 128 KiB LDS double-buffer, 16B-chunk XOR swizzle (slot^=row&7, inverse on the
// per-lane global source; LDS dest linear), per K-step {vmcnt(0); barrier} +
// 4 phases {ds_read; stage next; setprio(1) 16 MFMA setprio(0); barrier}.
// Epilogue theory: the MFMA D-layout scatters each store instr into 16x64B
// segments at 32KB pitch -> write path runs at ~1.8 TB/s (structure-invariant
// ~150us across R0/R4). Fix: after the K-loop, reuse the LDS as float[64][260]
// (row stride 1040B: 16B-aligned, bank-quad-optimal both sides). 4 chunks x 64
// rows: owning waves compute Matern + ds_write_b128 fragments; barrier; all 8
// waves read rows back and store 64 lanes x 16B = 1KB CONTIGUOUS per instr
// (full 128B lines), matching the fill's 6.2 TB/s pattern.
__global__ __launch_bounds__(512, 2) void matern_gemm(
    const _Float16* __restrict__ y1, const _Float16* __restrict__ y2,
    const float* __restrict__ sq1, const float* __restrict__ sq2,
    float* __restrict__ out) {
    __shared__ __align__(16) char smem[131072];
    _Float16* As0 = (_Float16*)smem;               // [2][BM*KH] = 64 KiB
    _Float16* Bs0 = (_Float16*)(smem + 65536);     // [2][BM*KH] = 64 KiB
    float (*Ls)[260] = (float (*)[260])smem;       // epilogue bounce, 66560 B

    const int tid  = threadIdx.x;
    const int wid  = tid >> 6;
    const int lane = tid & 63;

    // T1: XCD-bijective block swizzle (1024 % 8 == 0 -> simple form).
    const int bid = blockIdx.x;
    const int swz = (bid & 7) * 128 + (bid >> 3);
    const int bx = swz & 31;         // N-tile
    const int by = swz >> 5;         // M-tile
    const int row0 = by * BM;        // x1 rows
    const int col0 = bx * BM;        // x2 rows

    const int wr = wid >> 2;         // 0..1  (M half: 128 rows)
    const int wc = wid & 3;          // 0..3  (N quarter: 64 cols)
    const int wm = wr * 128;
    const int wn = wc * 64;
    const int fm = lane & 15;        // frag row within 16-row subtile
    const int q  = lane >> 4;        // k-quarter within K=32 (8 halves)
    const int x0 = q ^ (fm & 7);     // physical chunk for kk=0 (kk=1: x0^4)

    // staging: tile = 256 rows x 8 chunks(16B) = 2048 chunks; 512 thr -> 4
    // chunk-pairs (A+B) per thread per K-step. LDS dest linear: chunk c at c*16.
    // Global source k-chunk = (c&7) ^ (r&7), r = c>>3.
    int srow[4], skh[4];
    #pragma unroll
    for (int l = 0; l < 4; ++l) {
        int c = l * 512 + tid;
        int r = c >> 3, s = c & 7;
        srow[l] = r;
        skh[l] = ((s ^ (r & 7)) * 8);
    }

    f32x4 acc[8][4];
    const f32x4 zero = {0.f, 0.f, 0.f, 0.f};
    #pragma unroll
    for (int i = 0; i < 8; ++i)
        #pragma unroll
        for (int j = 0; j < 4; ++j) acc[i][j] = zero;

    auto stage_pair = [&](int kt, int buf, int l) {
        const int kb = kt * KH;
        const int c16 = (l * 512 + tid) * 16;   // wave-uniform base + lane*16
        async_load16(y1 + (size_t)(row0 + srow[l]) * DIM + kb + skh[l],
                     (char*)As0 + buf * 32768 + c16);
        async_load16(y2 + (size_t)(col0 + srow[l]) * DIM + kb + skh[l],
                     (char*)Bs0 + buf * 32768 + c16);
    };

    // Prologue: stage tile 0 fully.
    #pragma unroll
    for (int l = 0; l < 4; ++l) stage_pair(0, 0, l);

    #pragma unroll
    for (int kt = 0; kt < KSTEPS; ++kt) {
        const int cur = kt & 1;
        // K-step top: tile kt's 8 loads are the only outstanding vmem ops ->
        // vmcnt(0) is an exact counted wait. Barrier also guarantees all waves
        // finished reading buf[cur^1].
        asm volatile("s_waitcnt vmcnt(0) lgkmcnt(0)" ::: "memory");
        __builtin_amdgcn_s_barrier();

        const _Float16* Ab = As0 + cur * (BM * KH);
        const _Float16* Bb = Bs0 + cur * (BM * KH);
        half8 a[8];
        #pragma unroll
        for (int kk = 0; kk < 2; ++kk) {
            const int xk = x0 ^ (kk * 4);       // physical chunk this kk
            #pragma unroll
            for (int jh = 0; jh < 2; ++jh) {
                // phase p = kk*2 + jh
                if (jh == 0) {
                    #pragma unroll
                    for (int i = 0; i < 8; ++i)
                        a[i] = *(const half8*)(Ab + (wm + i * 16 + fm) * KH + xk * 8);
                }
                half8 b0 = *(const half8*)(Bb + (wn + (jh * 2 + 0) * 16 + fm) * KH + xk * 8);
                half8 b1 = *(const half8*)(Bb + (wn + (jh * 2 + 1) * 16 + fm) * KH + xk * 8);
                // stage next tile: 4 chunk-pairs in phase 0, 4 in phase 1
                if (kt + 1 < KSTEPS && kk == 0) {
                    stage_pair(kt + 1, cur ^ 1, jh * 2 + 0);
                    stage_pair(kt + 1, cur ^ 1, jh * 2 + 1);
                }
                __builtin_amdgcn_s_setprio(1);
                #pragma unroll
                for (int i = 0; i < 8; ++i) {
                    acc[i][jh * 2 + 0] = __builtin_amdgcn_mfma_f32_16x16x32_f16(b0, a[i], acc[i][jh * 2 + 0], 0, 0, 0);
                    acc[i][jh * 2 + 1] = __builtin_amdgcn_mfma_f32_16x16x32_f16(b1, a[i], acc[i][jh * 2 + 1], 0, 0, 0);
                }
                __builtin_amdgcn_s_setprio(0);
                if (!(kk == 1 && jh == 1))       // last phase: next step's top barrier covers
                    __builtin_amdgcn_s_barrier();
            }
        }
    }

    // --- Epilogue ---
    // D layout (swapped mfma(b,a)): M = lane&15 (=fm), N = q*4 + reg; value
    // acc[i][j][r] -> global (row0 + wm + i*16 + fm, col0 + wn + j*16 + q*4 + r).
    const int en = q * 4;
    float s1v[8];
    #pragma unroll
    for (int i = 0; i < 8; ++i)
        s1v[i] = sq1[row0 + wm + i * 16 + fm];
    f32x4 s2v[4];
    #pragma unroll
    for (int j = 0; j < 4; ++j)
        s2v[j] = *(const f32x4*)&sq2[col0 + wn + j * 16 + en];

    __syncthreads();   // all waves done reading As/Bs before aliasing as Ls

    #pragma unroll
    for (int c = 0; c < 4; ++c) {
        // chunk c covers tile M-rows [c*64, c*64+64): waves with wr == c>>1,
        // acc i in [ (c&1)*4, (c&1)*4+4 ).
        if (wr == (c >> 1)) {
            const int iBase = (c & 1) * 4;
            #pragma unroll
            for (int ii = 0; ii < 4; ++ii) {
                const int i = iBase + ii;
                const int lrow = ii * 16 + fm;      // row within chunk, 0..63
                #pragma unroll
                for (int j = 0; j < 4; ++j) {
                    f32x4 o;
                    #pragma unroll
                    for (int r = 0; r < 4; ++r) {
                        float d2 = s1v[i] + s2v[j][r] - 2.0f * acc[i][j][r];
                        // fmax(1e-30) subsumes clamp(d2,0) and clamp(dist,1e-15):
                        // dist = d2 * rsqrt(d2) >= 1e-15, never NaN.
                        d2 = fmaxf(d2, 1e-30f);
                        float dist = d2 * __frsqrt_rn(d2);
                        float t3 = 1.7320508075688772f * dist;
                        o[r] = (1.0f + t3) * __expf(-t3);
                    }
                    *(f32x4*)&Ls[lrow][wn + j * 16 + en] = o;
                }
            }
        }
        __syncthreads();   // fragments in place
        // all 8 waves: wave wid stores rows wid*8..wid*8+7; each store is
        // 64 lanes x 16B = 1KB contiguous (full 128B lines).
        const int gM0 = row0 + c * 64;
        #pragma unroll
        for (int rr = 0; rr < 8; ++rr) {
            const int lr = wid * 8 + rr;
            f32x4 v = *(const f32x4*)&Ls[lr][lane * 4];
            *(f32x4*)&out[(size_t)(gM0 + lr) * N2 + col0 + lane * 4] = v;
        }
        if (c < 3) __syncthreads();   // reads done before next chunk overwrites
    }
}

extern "C" void kernel_launch(void* const* d_in, const int* in_sizes, int n_in,
                              void* d_out, int out_size, void* d_ws, size_t ws_size,
                              hipStream_t stream) {
    const float* x1 = (const float*)d_in[0];
    const float* x2 = (const float*)d_in[1];
    const float* ls = (const float*)d_in[2];
    float* out = (float*)d_out;

    // workspace: adj[256]f32 | sq1[8192]f32 | sq2[8192]f32 | y1 fp16 4MB | y2 fp16 4MB
    char* ws = (char*)d_ws;
    float* adj = (float*)ws;
    float* sq1 = (float*)(ws + 1024);
    float* sq2 = (float*)(ws + 1024 + 32768);
    _Float16* y1 = (_Float16*)(ws + 66560);
    _Float16* y2 = (_Float16*)(ws + 66560 + 4194304);

    hipMemsetAsync(adj, 0, 256 * sizeof(float), stream);
    colmean_kernel<<<N1 / 16, 256, 0, stream>>>(x1, adj);
    quant_kernel<<<(N1 + N2) / 4, 256, 0, stream>>>(x1, x2, adj, ls, y1, y2, sq1, sq2);
    matern_gemm<<<dim3((N1 / BM) * (N2 / BM)), 512, 0, stream>>>(y1, y2, sq1, sq2, out);
}